// Round 1
// baseline (512.042 us; speedup 1.0000x reference)
//
#include <hip/hip_runtime.h>
#include <hip/hip_bf16.h>

// KNN_itc: out[b][n] = sum over support descriptors m (441) of top-3 (over 441
// query descriptors) cosine similarities, C=640 channels, bf16 MFMA compute.
//
// Pipeline:
//   1) norm_kernel  : inv L2 norm per descriptor (over C), coalesced along HW
//   2) xpose_kernel : [C][HW] -> [desc][C] transpose + scale + fp32->bf16,
//                     HW padded 441->448 with zero rows
//   3) gemm_top3    : per (b, n, 64-col tile): 7 row-tiles x 20 K-tiles,
//                     mfma_f32_16x16x32_bf16, running per-column top-3,
//                     one atomicAdd per block into zeroed d_out.

#define B_IMGS 75
#define N_CLS  5
#define C_DIM  640
#define HW     441
#define HWP    448
#define KTILES 20   // 640 / 32

typedef __attribute__((ext_vector_type(8))) short  short8;   // 8 x bf16 (4 VGPRs)
typedef __attribute__((ext_vector_type(4))) float  float4v;  // MFMA acc

// ---------------- kernel 1: inverse norms ----------------
__global__ void norm_kernel(const float* __restrict__ q, const float* __restrict__ S,
                            float* __restrict__ invq, float* __restrict__ invs) {
    int t = blockIdx.x * blockDim.x + threadIdx.x;
    const int total = (B_IMGS + N_CLS) * HW;
    if (t >= total) return;
    int img = t / HW;
    int hw  = t - img * HW;
    const float* src = (img < B_IMGS) ? (q + (size_t)img * C_DIM * HW)
                                      : (S + (size_t)(img - B_IMGS) * C_DIM * HW);
    float ss = 0.f;
#pragma unroll 8
    for (int c = 0; c < C_DIM; ++c) {
        float v = src[(size_t)c * HW + hw];   // lanes consecutive in hw: coalesced
        ss += v * v;
    }
    float inv = rsqrtf(ss);
    if (img < B_IMGS) invq[img * HW + hw] = inv;
    else              invs[(img - B_IMGS) * HW + hw] = inv;
}

// ------------- kernel 2: transpose + normalize + bf16 -------------
__global__ __launch_bounds__(256)
void xpose_kernel(const float* __restrict__ q, const float* __restrict__ S,
                  const float* __restrict__ invq, const float* __restrict__ invs,
                  __hip_bfloat16* __restrict__ qn, __hip_bfloat16* __restrict__ sn) {
    __shared__ float tile[64][65];             // +1 pad: conflict-free both phases
    int img = blockIdx.z;
    int hw0 = blockIdx.y * 64;
    int c0  = blockIdx.x * 64;
    const float* src; const float* inv; __hip_bfloat16* dst;
    if (img < B_IMGS) {
        src = q + (size_t)img * C_DIM * HW;
        inv = invq + img * HW;
        dst = qn + (size_t)img * HWP * C_DIM;
    } else {
        src = S + (size_t)(img - B_IMGS) * C_DIM * HW;
        inv = invs + (img - B_IMGS) * HW;
        dst = sn + (size_t)(img - B_IMGS) * HWP * C_DIM;
    }
    int tid = threadIdx.x;
    int hl  = tid & 63;        // hw-local for load phase
    int qd4 = tid >> 6;        // 0..3
    int hwg = hw0 + hl;
    float invv = (hwg < HW) ? inv[hwg] : 0.f;
#pragma unroll
    for (int i = 0; i < 16; ++i) {
        int cl = qd4 * 16 + i;
        float v = 0.f;
        if (hwg < HW) v = src[(size_t)(c0 + cl) * HW + hwg] * invv;  // coalesced read
        tile[cl][hl] = v;
    }
    __syncthreads();
    int cl2 = tid & 63;        // c-local for store phase
#pragma unroll
    for (int j = 0; j < 16; ++j) {
        int hwl = qd4 * 16 + j;
        // coalesced 128B store along C; pad rows (hw>=441) get zeros
        dst[(size_t)(hw0 + hwl) * C_DIM + c0 + cl2] = __float2bfloat16(tile[cl2][hwl]);
    }
}

// ------------- kernel 3: MFMA GEMM + fused per-column top-3 -------------
__global__ __launch_bounds__(256)
void gemm_top3_kernel(const __hip_bfloat16* __restrict__ qn,
                      const __hip_bfloat16* __restrict__ sn,
                      float* __restrict__ out) {
    __shared__ __hip_bfloat16 As[64 * 32];     // 64 q-rows  x 32 k
    __shared__ __hip_bfloat16 Bs[64 * 32];     // 64 s-cols  x 32 k
    __shared__ float simb[64 * 65];            // 64x64 sim tile (+pad)

    int mt = blockIdx.x, n = blockIdx.y, b = blockIdx.z;
    int tid  = threadIdx.x;
    int wave = tid >> 6;
    int lane = tid & 63;

    const __hip_bfloat16* qb = qn + (size_t)b * HWP * C_DIM;
    const __hip_bfloat16* sb = sn + (size_t)n * HWP * C_DIM + (size_t)mt * 64 * C_DIM;

    // staging: thread t moves one 16B chunk per tile per k-iter
    int srow = tid >> 2;           // 0..63 row within tile
    int soff = (tid & 3) * 8;      // element offset within 32-k

    // per-column running top-3 (threads 0..63 own one column each)
    float t0 = -1e30f, t1 = -1e30f, t2 = -1e30f;

    // fragment addresses (constant across loop)
    const int a_off = (wave * 16 + (lane & 15)) * 32 + (lane >> 4) * 8;
    const int b_off0 = ((lane & 15)) * 32 + (lane >> 4) * 8;

    for (int rt = 0; rt < 7; ++rt) {
        float4v acc0 = {0.f,0.f,0.f,0.f}, acc1 = {0.f,0.f,0.f,0.f};
        float4v acc2 = {0.f,0.f,0.f,0.f}, acc3 = {0.f,0.f,0.f,0.f};
        const __hip_bfloat16* qrow  = qb + (size_t)(rt * 64 + srow) * C_DIM + soff;
        const __hip_bfloat16* srowp = sb + (size_t)srow * C_DIM + soff;

        for (int kt = 0; kt < KTILES; ++kt) {
            short8 av = *(const short8*)(qrow  + kt * 32);
            short8 bv = *(const short8*)(srowp + kt * 32);
            __syncthreads();                     // prior frag reads done
            *(short8*)(As + srow * 32 + soff) = av;
            *(short8*)(Bs + srow * 32 + soff) = bv;
            __syncthreads();                     // staging visible

            short8 af  = *(const short8*)(As + a_off);
            short8 bf0 = *(const short8*)(Bs + b_off0);
            short8 bf1 = *(const short8*)(Bs + b_off0 + 16 * 32);
            short8 bf2 = *(const short8*)(Bs + b_off0 + 32 * 32);
            short8 bf3 = *(const short8*)(Bs + b_off0 + 48 * 32);
            acc0 = __builtin_amdgcn_mfma_f32_16x16x32_bf16(af, bf0, acc0, 0, 0, 0);
            acc1 = __builtin_amdgcn_mfma_f32_16x16x32_bf16(af, bf1, acc1, 0, 0, 0);
            acc2 = __builtin_amdgcn_mfma_f32_16x16x32_bf16(af, bf2, acc2, 0, 0, 0);
            acc3 = __builtin_amdgcn_mfma_f32_16x16x32_bf16(af, bf3, acc3, 0, 0, 0);
        }

        // ---- epilogue: sim tile -> LDS, then per-column top-3 update ----
        __syncthreads();                         // previous rt's scan finished
        int rbase = wave * 16 + (lane >> 4) * 4; // C layout: row=(lane>>4)*4+reg
        int cbase = lane & 15;                   //           col=lane&15
#pragma unroll
        for (int r = 0; r < 4; ++r) {
            simb[(rbase + r) * 65 + cbase     ] = acc0[r];
            simb[(rbase + r) * 65 + cbase + 16] = acc1[r];
            simb[(rbase + r) * 65 + cbase + 32] = acc2[r];
            simb[(rbase + r) * 65 + cbase + 48] = acc3[r];
        }
        __syncthreads();
        if (tid < 64) {
            int nval = HW - rt * 64; if (nval > 64) nval = 64;  // mask pad rows
            for (int r = 0; r < nval; ++r) {
                float v = simb[r * 65 + tid];
                if (v > t0)      { t2 = t1; t1 = t0; t0 = v; }
                else if (v > t1) { t2 = t1; t1 = v; }
                else if (v > t2) { t2 = v; }
            }
        }
    }

    // ---- block reduction of per-column top-3 sums, one atomic per block ----
    float s = 0.f;
    if (tid < 64 && (mt * 64 + tid) < HW) s = t0 + t1 + t2;  // mask pad columns
    __syncthreads();
    if (tid < 64) simb[tid] = s;
    __syncthreads();
    if (tid == 0) {
        float tot = 0.f;
#pragma unroll
        for (int i = 0; i < 64; ++i) tot += simb[i];
        atomicAdd(&out[b * N_CLS + n], tot);
    }
}

extern "C" void kernel_launch(void* const* d_in, const int* in_sizes, int n_in,
                              void* d_out, int out_size, void* d_ws, size_t ws_size,
                              hipStream_t stream) {
    const float* q = (const float*)d_in[0];
    const float* S = (const float*)d_in[1];
    float* out = (float*)d_out;

    char* ws = (char*)d_ws;
    size_t off = 0;
    __hip_bfloat16* qn = (__hip_bfloat16*)(ws + off);
    off += (size_t)B_IMGS * HWP * C_DIM * 2;  off = (off + 255) & ~(size_t)255;
    __hip_bfloat16* sn = (__hip_bfloat16*)(ws + off);
    off += (size_t)N_CLS * HWP * C_DIM * 2;   off = (off + 255) & ~(size_t)255;
    float* invq = (float*)(ws + off);
    off += (size_t)B_IMGS * HW * 4;           off = (off + 255) & ~(size_t)255;
    float* invs = (float*)(ws + off);

    hipMemsetAsync(d_out, 0, (size_t)out_size * sizeof(float), stream);

    int totald = (B_IMGS + N_CLS) * HW;
    norm_kernel<<<dim3((totald + 255) / 256), dim3(256), 0, stream>>>(q, S, invq, invs);
    xpose_kernel<<<dim3(C_DIM / 64, HWP / 64, B_IMGS + N_CLS), dim3(256), 0, stream>>>(
        q, S, invq, invs, qn, sn);
    gemm_top3_kernel<<<dim3(7, N_CLS, B_IMGS), dim3(256), 0, stream>>>(qn, sn, out);
}

// Round 2
// 417.326 us; speedup vs baseline: 1.2270x; 1.2270x over previous
//
#include <hip/hip_runtime.h>
#include <hip/hip_bf16.h>

// KNN_itc: out[b][n] = sum over support descriptors m (441) of top-3 (over 441
// query descriptors) cosine similarities, C=640, bf16 MFMA.
//
// R2 structure: block = (b, n, 64-col tile). Support tile resident in LDS
// (two K=320 phases, padded stride). A fragments read directly from global
// (L2-hot, XCD-swizzled). 28 accs/wave, no inner-loop barriers, in-register
// top-3 with shuffle merges, one atomicAdd per block.

#define B_IMGS 75
#define N_CLS  5
#define C_DIM  640
#define HW     441
#define HWP    448
#define BC     64     // support cols per block
#define KPH    320    // K elems per LDS phase
#define KT_PH  10     // 320/32 k-tiles per phase
#define BSTR   328    // LDS B stride in elems (320 + 8 pad; 656B = 41*16B)

typedef __attribute__((ext_vector_type(8))) short  short8;   // 8 x bf16
typedef __attribute__((ext_vector_type(4))) float  float4v;  // MFMA acc

__device__ __forceinline__ void ins3(float& t0, float& t1, float& t2, float v) {
    float m  = fminf(t0, v);
    t0 = fmaxf(t0, v);
    float m2 = fminf(t1, m);
    t1 = fmaxf(t1, m);
    t2 = fmaxf(t2, m2);
}

// ---------------- kernel 1: inverse norms (4-way C split) ----------------
__global__ __launch_bounds__(256)
void norm_kernel(const float* __restrict__ q, const float* __restrict__ S,
                 float* __restrict__ invq, float* __restrict__ invs) {
    __shared__ float part[4][64];
    const int total = (B_IMGS + N_CLS) * HW;
    int l = threadIdx.x & 63, p = threadIdx.x >> 6;
    int pos = blockIdx.x * 64 + l;
    bool ok = pos < total;
    int posc = ok ? pos : (total - 1);
    int img = posc / HW;
    int hw  = posc - img * HW;
    const float* src = (img < B_IMGS) ? (q + (size_t)img * C_DIM * HW)
                                      : (S + (size_t)(img - B_IMGS) * C_DIM * HW);
    float ss = 0.f;
#pragma unroll 8
    for (int c = p * 160; c < (p + 1) * 160; ++c) {
        float v = src[(size_t)c * HW + hw];
        ss += v * v;
    }
    part[p][l] = ss;
    __syncthreads();
    if (threadIdx.x < 64) {
        float tot = part[0][l] + part[1][l] + part[2][l] + part[3][l];
        float inv = rsqrtf(tot);
        if (ok) {
            if (img < B_IMGS) invq[img * HW + hw] = inv;
            else              invs[(img - B_IMGS) * HW + hw] = inv;
        }
    }
}

// ------------- kernel 2: transpose + normalize + bf16 -------------
__global__ __launch_bounds__(256)
void xpose_kernel(const float* __restrict__ q, const float* __restrict__ S,
                  const float* __restrict__ invq, const float* __restrict__ invs,
                  __hip_bfloat16* __restrict__ qn, __hip_bfloat16* __restrict__ sn) {
    __shared__ float tile[64][65];
    int img = blockIdx.z;
    int hw0 = blockIdx.y * 64;
    int c0  = blockIdx.x * 64;
    const float* src; const float* inv; __hip_bfloat16* dst;
    if (img < B_IMGS) {
        src = q + (size_t)img * C_DIM * HW;
        inv = invq + img * HW;
        dst = qn + (size_t)img * HWP * C_DIM;
    } else {
        src = S + (size_t)(img - B_IMGS) * C_DIM * HW;
        inv = invs + (img - B_IMGS) * HW;
        dst = sn + (size_t)(img - B_IMGS) * HWP * C_DIM;
    }
    int tid = threadIdx.x;
    int hl  = tid & 63;
    int qd4 = tid >> 6;
    int hwg = hw0 + hl;
    float invv = (hwg < HW) ? inv[hwg] : 0.f;
#pragma unroll
    for (int i = 0; i < 16; ++i) {
        int cl = qd4 * 16 + i;
        float v = 0.f;
        if (hwg < HW) v = src[(size_t)(c0 + cl) * HW + hwg] * invv;
        tile[cl][hl] = v;
    }
    __syncthreads();
    int cl2 = tid & 63;
#pragma unroll
    for (int j = 0; j < 16; ++j) {
        int hwl = qd4 * 16 + j;
        dst[(size_t)(hw0 + hwl) * C_DIM + c0 + cl2] = __float2bfloat16(tile[cl2][hwl]);
    }
}

// ------------- kernel 3: MFMA GEMM + fused in-register top-3 -------------
__global__ __launch_bounds__(256, 2)
void gemm_top3_kernel(const __hip_bfloat16* __restrict__ qn,
                      const __hip_bfloat16* __restrict__ sn,
                      float* __restrict__ out) {
    __shared__ __hip_bfloat16 Bs[BC * BSTR];   // 41,984 B
    __shared__ float mrg[4][BC][3];            //  3,072 B

    // XCD-grouping swizzle: same image b -> same id%8 -> same XCD (heuristic)
    int id  = blockIdx.x;
    int xcd = id & 7;
    int j8  = id >> 3;
    int b   = (j8 / 35) * 8 + xcd;
    if (b >= B_IMGS) return;
    int inner = j8 % 35;
    int n  = inner / 7;
    int mt = inner % 7;

    int tid  = threadIdx.x;
    int w    = tid >> 6;
    int lane = tid & 63;
    int c16  = lane & 15;
    int quad = lane >> 4;

    const __hip_bfloat16* qb = qn + (size_t)b * HWP * C_DIM;
    const __hip_bfloat16* sb = sn + (size_t)n * HWP * C_DIM + (size_t)mt * BC * C_DIM;

    float4v acc[7][4];
#pragma unroll
    for (int r = 0; r < 7; ++r)
#pragma unroll
        for (int j = 0; j < 4; ++j)
            acc[r][j] = (float4v){0.f, 0.f, 0.f, 0.f};

    // A fragment row pointers: lane holds A[m=c16][k=quad*8..+7]
    const __hip_bfloat16* aptr[7];
#pragma unroll
    for (int r = 0; r < 7; ++r)
        aptr[r] = qb + (size_t)(r * 64 + w * 16 + c16) * C_DIM + quad * 8;

    const int boff = c16 * BSTR + quad * 8;

    for (int ph = 0; ph < 2; ++ph) {
        __syncthreads();   // prior phase's fragment reads complete
        // ---- stage 64 x 320 support slice into LDS (10 x 16B per thread) ----
#pragma unroll
        for (int i = 0; i < KT_PH; ++i) {
            int cid = tid + i * 256;
            int row = cid / 40;                // 40 chunks of 8 elems per row
            int off = (cid - row * 40) * 8;
            *(short8*)(Bs + row * BSTR + off) =
                *(const short8*)(sb + (size_t)row * C_DIM + ph * KPH + off);
        }
        __syncthreads();

        const int kbase = ph * KPH;
        // 1-deep A prefetch
        short8 a_c[7];
#pragma unroll
        for (int r = 0; r < 7; ++r)
            a_c[r] = *(const short8*)(aptr[r] + kbase);

        for (int kt = 0; kt < KT_PH; ++kt) {
            short8 a_n[7];
            if (kt < KT_PH - 1) {
#pragma unroll
                for (int r = 0; r < 7; ++r)
                    a_n[r] = *(const short8*)(aptr[r] + kbase + (kt + 1) * 32);
            }
            short8 b_c[4];
#pragma unroll
            for (int j = 0; j < 4; ++j)
                b_c[j] = *(const short8*)(Bs + j * 16 * BSTR + boff + kt * 32);
#pragma unroll
            for (int r = 0; r < 7; ++r)
#pragma unroll
                for (int j = 0; j < 4; ++j)
                    acc[r][j] = __builtin_amdgcn_mfma_f32_16x16x32_bf16(
                        a_c[r], b_c[j], acc[r][j], 0, 0, 0);
            if (kt < KT_PH - 1) {
#pragma unroll
                for (int r = 0; r < 7; ++r) a_c[r] = a_n[r];
            }
        }
    }

    // ---- in-register top-3 over this wave's 112 rows, per owned column ----
    float T0[4], T1[4], T2[4];
#pragma unroll
    for (int j = 0; j < 4; ++j) { T0[j] = -1e30f; T1[j] = -1e30f; T2[j] = -1e30f; }
#pragma unroll
    for (int r = 0; r < 7; ++r)
#pragma unroll
        for (int j = 0; j < 4; ++j)
#pragma unroll
            for (int g = 0; g < 4; ++g) {
                int row = r * 64 + w * 16 + quad * 4 + g;   // C layout: row=quad*4+reg
                float v = (row < HW) ? acc[r][j][g] : -1e30f;
                ins3(T0[j], T1[j], T2[j], v);
            }

    // quad-butterfly merge (rows spread over lane bits 4,5)
#pragma unroll
    for (int j = 0; j < 4; ++j) {
#pragma unroll
        for (int d = 16; d <= 32; d <<= 1) {
            float o0 = __shfl_xor(T0[j], d, 64);
            float o1 = __shfl_xor(T1[j], d, 64);
            float o2 = __shfl_xor(T2[j], d, 64);
            ins3(T0[j], T1[j], T2[j], o0);
            ins3(T0[j], T1[j], T2[j], o1);
            ins3(T0[j], T1[j], T2[j], o2);
        }
    }

    // cross-wave merge via LDS
    if (quad == 0) {
#pragma unroll
        for (int j = 0; j < 4; ++j) {
            mrg[w][j * 16 + c16][0] = T0[j];
            mrg[w][j * 16 + c16][1] = T1[j];
            mrg[w][j * 16 + c16][2] = T2[j];
        }
    }
    __syncthreads();
    if (tid < 64) {
        int col = tid;
        float t0 = mrg[0][col][0], t1 = mrg[0][col][1], t2 = mrg[0][col][2];
#pragma unroll
        for (int ww = 1; ww < 4; ++ww) {
            ins3(t0, t1, t2, mrg[ww][col][0]);
            ins3(t0, t1, t2, mrg[ww][col][1]);
            ins3(t0, t1, t2, mrg[ww][col][2]);
        }
        float s = (mt * BC + col < HW) ? (t0 + t1 + t2) : 0.f;
#pragma unroll
        for (int d = 32; d >= 1; d >>= 1) s += __shfl_xor(s, d, 64);
        if (tid == 0) atomicAdd(&out[b * N_CLS + n], s);
    }
}

extern "C" void kernel_launch(void* const* d_in, const int* in_sizes, int n_in,
                              void* d_out, int out_size, void* d_ws, size_t ws_size,
                              hipStream_t stream) {
    const float* q = (const float*)d_in[0];
    const float* S = (const float*)d_in[1];
    float* out = (float*)d_out;

    char* ws = (char*)d_ws;
    size_t off = 0;
    __hip_bfloat16* qn = (__hip_bfloat16*)(ws + off);
    off += (size_t)B_IMGS * HWP * C_DIM * 2;  off = (off + 255) & ~(size_t)255;
    __hip_bfloat16* sn = (__hip_bfloat16*)(ws + off);
    off += (size_t)N_CLS * HWP * C_DIM * 2;   off = (off + 255) & ~(size_t)255;
    float* invq = (float*)(ws + off);
    off += (size_t)B_IMGS * HW * 4;           off = (off + 255) & ~(size_t)255;
    float* invs = (float*)(ws + off);

    hipMemsetAsync(d_out, 0, (size_t)out_size * sizeof(float), stream);

    int totald = (B_IMGS + N_CLS) * HW;
    norm_kernel<<<dim3((totald + 63) / 64), dim3(256), 0, stream>>>(q, S, invq, invs);
    xpose_kernel<<<dim3(C_DIM / 64, HWP / 64, B_IMGS + N_CLS), dim3(256), 0, stream>>>(
        q, S, invq, invs, qn, sn);
    // 8 XCD groups x 350 slots (b-groups of 8 x 35 inner); dead blocks (b>=75) exit
    gemm_top3_kernel<<<dim3(8 * 350), dim3(256), 0, stream>>>(qn, sn, out);
}

// Round 3
// 313.744 us; speedup vs baseline: 1.6320x; 1.3301x over previous
//
#include <hip/hip_runtime.h>
#include <hip/hip_bf16.h>

// KNN_itc: out[b][n] = sum over support descriptors m (441) of top-3 (over 441
// query descriptors) cosine similarities, C=640, bf16 MFMA.
//
// R3 structure:
//   prep_kernel : fused norm + transpose + bf16, writing MFMA-fragment-major
//                 tiled layout: chunk[(img*28+rb)*20+kt][512] where element
//                 (row=rb*16+r16, c=kt*32+k32) sits at chunk*512 + r16*32 + k32.
//                 => every gemm fragment load is one coalesced 1KiB wave load.
//   gemm_top3   : NO LDS / NO barriers in K-loop. Per kt: 7 A-frag + 4 B-frag
//                 coalesced global loads (L2/L1-hot) + 28 MFMAs, 1-deep
//                 prefetch. In-register top-3 + shuffle merge + one atomicAdd.

#define B_IMGS 75
#define N_CLS  5
#define C_DIM  640
#define HW     441
#define HWP    448
#define NKT    20            // 640 / 32 k-chunks
#define NRB    28            // 448 / 16 row-blocks per image
#define CHUNK  512           // 16 rows x 32 k elems

typedef __attribute__((ext_vector_type(8))) short  short8;   // 8 x bf16
typedef __attribute__((ext_vector_type(4))) float  float4v;  // MFMA acc

__device__ __forceinline__ void ins3(float& t0, float& t1, float& t2, float v) {
    float m  = fminf(t0, v);
    t0 = fmaxf(t0, v);
    float m2 = fminf(t1, m);
    t1 = fmaxf(t1, m);
    t2 = fmaxf(t2, m2);
}

__device__ __forceinline__ short bf16bits(float x) {
    __hip_bfloat16 h = __float2bfloat16(x);
    return *(short*)&h;
}

// ---------- fused prepass: norm + transpose + bf16 + fragment-tiled write ----------
__global__ __launch_bounds__(256)
void prep_kernel(const float* __restrict__ q, const float* __restrict__ S,
                 __hip_bfloat16* __restrict__ qn2, __hip_bfloat16* __restrict__ sn2) {
    __shared__ float part[4][64];
    __shared__ float inv[64];
    __shared__ float tile[64][65];      // [c_local][hw_local], +1 pad

    int img = blockIdx.x / 7;           // 0..79  (0..74 = q, 75..79 = S)
    int h0  = blockIdx.x % 7;           // 64-row hw tile
    const float* src;
    __hip_bfloat16* dst;
    if (img < B_IMGS) {
        src = q + (size_t)img * C_DIM * HW;
        dst = qn2 + (size_t)img * NRB * NKT * CHUNK;
    } else {
        src = S + (size_t)(img - B_IMGS) * C_DIM * HW;
        dst = sn2 + (size_t)(img - B_IMGS) * NRB * NKT * CHUNK;
    }
    int t  = threadIdx.x;
    int hl = t & 63;
    int p  = t >> 6;
    int hw = h0 * 64 + hl;
    bool ok = hw < HW;
    int hwc = ok ? hw : (HW - 1);

    // phase 1: sum of squares over this thread's 160-channel slice
    float ss = 0.f;
#pragma unroll 8
    for (int c = p * 160; c < (p + 1) * 160; ++c) {
        float v = src[(size_t)c * HW + hwc];
        ss += v * v;
    }
    part[p][hl] = ss;
    __syncthreads();
    if (t < 64) {
        float tot = part[0][hl] + part[1][hl] + part[2][hl] + part[3][hl];
        inv[hl] = ok ? rsqrtf(tot) : 0.f;   // pad rows -> zeros
    }
    __syncthreads();

    // phase 2: 10 slabs of 64 channels; L2-hot re-read -> LDS -> tiled write
    float iv = inv[hl];
    for (int sl = 0; sl < 10; ++sl) {
        if (sl) __syncthreads();
#pragma unroll
        for (int i = 0; i < 16; ++i) {
            int cl = p * 16 + i;
            tile[cl][hl] = src[(size_t)(sl * 64 + cl) * HW + hwc] * iv;
        }
        __syncthreads();
        // write two 32-k chunk columns (kt = sl*2, sl*2+1)
#pragma unroll
        for (int s = 0; s < 2; ++s) {
            int idx = t + s * 256;          // 0..511
            int ktl = idx >> 8;             // 0/1
            int rl  = (idx & 255) >> 2;     // hw local row 0..63
            int k8  = (idx & 3) * 8;
            short8 v;
#pragma unroll
            for (int j = 0; j < 8; ++j)
                v[j] = bf16bits(tile[ktl * 32 + k8 + j][rl]);
            int rb = h0 * 4 + (rl >> 4);
            size_t off = ((size_t)rb * NKT + sl * 2 + ktl) * CHUNK + (rl & 15) * 32 + k8;
            *(short8*)(dst + off) = v;
        }
    }
}

// ------------- gemm + fused top-3: no LDS, no barriers in K-loop -------------
__global__ __launch_bounds__(256, 2)
void gemm_top3_kernel(const __hip_bfloat16* __restrict__ qn2,
                      const __hip_bfloat16* __restrict__ sn2,
                      float* __restrict__ out) {
    __shared__ float mrg[4][64][3];

    // XCD-grouping swizzle: all 35 (n,mt) blocks of image b on one XCD
    int id  = blockIdx.x;
    int xcd = id & 7;
    int j8  = id >> 3;
    int b   = (j8 / 35) * 8 + xcd;
    if (b >= B_IMGS) return;
    int inner = j8 % 35;
    int n  = inner / 7;
    int mt = inner % 7;

    int tid  = threadIdx.x;
    int w    = tid >> 6;
    int lane = tid & 63;
    int c16  = lane & 15;
    int quad = lane >> 4;
    int frag = c16 * 32 + quad * 8;     // within-chunk fragment offset

    // A chunk bases: rfrag r -> rb = r*4 + w
    const __hip_bfloat16* aptr[7];
#pragma unroll
    for (int r = 0; r < 7; ++r)
        aptr[r] = qn2 + ((size_t)b * NRB + r * 4 + w) * NKT * CHUNK + frag;
    // B chunk bases: jfrag j -> rb' = mt*4 + j  (within class n)
    const __hip_bfloat16* bptr[4];
#pragma unroll
    for (int j = 0; j < 4; ++j)
        bptr[j] = sn2 + ((size_t)n * NRB + mt * 4 + j) * NKT * CHUNK + frag;

    float4v acc[7][4];
#pragma unroll
    for (int r = 0; r < 7; ++r)
#pragma unroll
        for (int j = 0; j < 4; ++j)
            acc[r][j] = (float4v){0.f, 0.f, 0.f, 0.f};

    short8 a_c[7], b_c[4];
#pragma unroll
    for (int r = 0; r < 7; ++r) a_c[r] = *(const short8*)(aptr[r]);
#pragma unroll
    for (int j = 0; j < 4; ++j) b_c[j] = *(const short8*)(bptr[j]);

    for (int kt = 0; kt < NKT; ++kt) {
        short8 a_n[7], b_n[4];
        if (kt < NKT - 1) {
#pragma unroll
            for (int r = 0; r < 7; ++r)
                a_n[r] = *(const short8*)(aptr[r] + (kt + 1) * CHUNK);
#pragma unroll
            for (int j = 0; j < 4; ++j)
                b_n[j] = *(const short8*)(bptr[j] + (kt + 1) * CHUNK);
        }
#pragma unroll
        for (int r = 0; r < 7; ++r)
#pragma unroll
            for (int j = 0; j < 4; ++j)
                acc[r][j] = __builtin_amdgcn_mfma_f32_16x16x32_bf16(
                    a_c[r], b_c[j], acc[r][j], 0, 0, 0);
        if (kt < NKT - 1) {
#pragma unroll
            for (int r = 0; r < 7; ++r) a_c[r] = a_n[r];
#pragma unroll
            for (int j = 0; j < 4; ++j) b_c[j] = b_n[j];
        }
    }

    // ---- in-register top-3 over this wave's 112 rows, per owned column ----
    float T0[4], T1[4], T2[4];
#pragma unroll
    for (int j = 0; j < 4; ++j) { T0[j] = -1e30f; T1[j] = -1e30f; T2[j] = -1e30f; }
#pragma unroll
    for (int r = 0; r < 7; ++r)
#pragma unroll
        for (int j = 0; j < 4; ++j)
#pragma unroll
            for (int g = 0; g < 4; ++g) {
                int row = r * 64 + w * 16 + quad * 4 + g;   // C layout: row=quad*4+reg
                float v = (row < HW) ? acc[r][j][g] : -1e30f;
                ins3(T0[j], T1[j], T2[j], v);
            }

    // quad-butterfly merge (rows spread over lane bits 4,5)
#pragma unroll
    for (int j = 0; j < 4; ++j) {
#pragma unroll
        for (int d = 16; d <= 32; d <<= 1) {
            float o0 = __shfl_xor(T0[j], d, 64);
            float o1 = __shfl_xor(T1[j], d, 64);
            float o2 = __shfl_xor(T2[j], d, 64);
            ins3(T0[j], T1[j], T2[j], o0);
            ins3(T0[j], T1[j], T2[j], o1);
            ins3(T0[j], T1[j], T2[j], o2);
        }
    }

    // cross-wave merge via LDS
    if (quad == 0) {
#pragma unroll
        for (int j = 0; j < 4; ++j) {
            mrg[w][j * 16 + c16][0] = T0[j];
            mrg[w][j * 16 + c16][1] = T1[j];
            mrg[w][j * 16 + c16][2] = T2[j];
        }
    }
    __syncthreads();
    if (tid < 64) {
        int col = tid;
        float t0 = mrg[0][col][0], t1 = mrg[0][col][1], t2 = mrg[0][col][2];
#pragma unroll
        for (int ww = 1; ww < 4; ++ww) {
            ins3(t0, t1, t2, mrg[ww][col][0]);
            ins3(t0, t1, t2, mrg[ww][col][1]);
            ins3(t0, t1, t2, mrg[ww][col][2]);
        }
        float s = (mt * 64 + col < HW) ? (t0 + t1 + t2) : 0.f;
#pragma unroll
        for (int d = 32; d >= 1; d >>= 1) s += __shfl_xor(s, d, 64);
        if (tid == 0) atomicAdd(&out[b * N_CLS + n], s);
    }
}

extern "C" void kernel_launch(void* const* d_in, const int* in_sizes, int n_in,
                              void* d_out, int out_size, void* d_ws, size_t ws_size,
                              hipStream_t stream) {
    const float* q = (const float*)d_in[0];
    const float* S = (const float*)d_in[1];
    float* out = (float*)d_out;

    char* ws = (char*)d_ws;
    size_t off = 0;
    __hip_bfloat16* qn2 = (__hip_bfloat16*)(ws + off);
    off += (size_t)B_IMGS * NRB * NKT * CHUNK * 2;  off = (off + 255) & ~(size_t)255;
    __hip_bfloat16* sn2 = (__hip_bfloat16*)(ws + off);

    hipMemsetAsync(d_out, 0, (size_t)out_size * sizeof(float), stream);

    prep_kernel<<<dim3(80 * 7), dim3(256), 0, stream>>>(q, S, qn2, sn2);
    // 8 XCD groups x 350 slots; dead blocks (b>=75) exit immediately
    gemm_top3_kernel<<<dim3(8 * 350), dim3(256), 0, stream>>>(qn2, sn2, out);
}